// Round 11
// baseline (213.320 us; speedup 1.0000x reference)
//
#include <hip/hip_runtime.h>
#include <cstdint>
#include <cstddef>
#include <math.h>

#define B_   2
#define T_   2048
#define DM   1024
#define NH   16
#define DH   64
#define DC1  384
#define DCC  256
#define DR   32
#define BT   (B_*T_)
#define DQK  96      // DH + DR

typedef __bf16 bf16x8 __attribute__((ext_vector_type(8)));
typedef __bf16 bf16x4 __attribute__((ext_vector_type(4)));
typedef float  f32x4  __attribute__((ext_vector_type(4)));
typedef short  s16x4  __attribute__((ext_vector_type(4)));
#define MFMA16(a,b,c) __builtin_amdgcn_mfma_f32_16x16x32_bf16((a),(b),(c),0,0,0)

// 16x16x16 bf16 MFMA (K=16): A/B = 4 bf16 (2 VGPR), C/D = 4 f32.
__device__ __forceinline__ f32x4 mfma_pv(bf16x4 a, bf16x4 b, f32x4 c) {
#if __has_builtin(__builtin_amdgcn_mfma_f32_16x16x16bf16_1k)
  return __builtin_amdgcn_mfma_f32_16x16x16bf16_1k(
      __builtin_bit_cast(s16x4, a), __builtin_bit_cast(s16x4, b), c, 0, 0, 0);
#else
  f32x4 d = c;
  asm volatile("v_mfma_f32_16x16x16_bf16 %0, %1, %2, %0"
               : "+v"(d) : "v"(a), "v"(b));
  return d;
#endif
}

__device__ __forceinline__ float exp2_fast(float x) {
#if __has_builtin(__builtin_amdgcn_exp2f)
  return __builtin_amdgcn_exp2f(x);
#else
  float r; asm("v_exp_f32 %0, %1" : "=v"(r) : "v"(x)); return r;
#endif
}

__device__ __forceinline__ void gld16(const __bf16* g, __bf16* l) {
  __builtin_amdgcn_global_load_lds(
      (const __attribute__((address_space(1))) void*)g,
      (__attribute__((address_space(3))) void*)l, 16, 0, 0);
}

struct GemmDesc {
  const __bf16* A;
  const __bf16* Bt;
  void* C;
  int lda, ldb, ldc, K, Nvalid, ntx, blk0;
};
struct GemmBatch { GemmDesc d[4]; int nd; };

// ---------------------------------------------------------------------------
// Multi-GEMM, single-barrier double-buffered gld16 pipeline, BK=64, 4 waves.
// PROVEN CORRECT (r10-r12 bit-identical experiment). TM,TN in {64,128}.
// ---------------------------------------------------------------------------
template<typename CT, int TM, int TN>
__global__ __launch_bounds__(256) void gemm_multi(GemmBatch gb) {
  constexpr int MT  = TM / 32;
  constexpr int NT  = TN / 32;
  constexpr int APW = (TM * 4) / 256;
  constexpr int BPW = (TN * 4) / 256;
  __shared__ __align__(16) __bf16 As[4 * TM * 32];
  __shared__ __align__(16) __bf16 Bs[4 * TN * 32];
  const int bid = blockIdx.x;
  int di = gb.nd - 1;
  while (di > 0 && bid < gb.d[di].blk0) di--;
  const GemmDesc D = gb.d[di];
  const int local = bid - D.blk0;
  const int by = local / D.ntx, bx = local - by * D.ntx;
  const int m0 = by * TM, n0 = bx * TN;

  const int tid = threadIdx.x;
  const int w = tid >> 6, l = tid & 63;
  const int g = l >> 4, ln = l & 15;
  const int wm = w >> 1, wn = w & 1;

  const __bf16* gA[APW]; int aoff[APW];
  #pragma unroll
  for (int i = 0; i < APW; i++) {
    int slot = w * (APW * 64) + i * 64 + l;
    gA[i] = D.A + (size_t)(m0 + (slot >> 2)) * D.lda + (slot & 3) * 8;
    aoff[i] = (w * (APW * 64) + i * 64) * 8;
  }
  const __bf16* gB[BPW]; int boff[BPW];
  #pragma unroll
  for (int i = 0; i < BPW; i++) {
    int slot = w * (BPW * 64) + i * 64 + l;
    int bn = n0 + (slot >> 2); if (bn >= D.Nvalid) bn = D.Nvalid - 1;
    gB[i] = D.Bt + (size_t)bn * D.ldb + (slot & 3) * 8;
    boff[i] = (w * (BPW * 64) + i * 64) * 8;
  }

  f32x4 acc[MT][NT];
  #pragma unroll
  for (int i = 0; i < MT; i++)
    #pragma unroll
    for (int j = 0; j < NT; j++) acc[i][j] = (f32x4){0.f, 0.f, 0.f, 0.f};

  #pragma unroll
  for (int ch = 0; ch < 2; ch++) {
    #pragma unroll
    for (int i = 0; i < APW; i++)
      gld16(gA[i] + ch * 32, As + ch * TM * 32 + aoff[i]);
    #pragma unroll
    for (int i = 0; i < BPW; i++)
      gld16(gB[i] + ch * 32, Bs + ch * TN * 32 + boff[i]);
  }

  const int nper = D.K >> 6;
  int p = 0;
  for (int it = 0; it < nper; ++it) {
    __syncthreads();
    if (it + 1 < nper) {
      const int ko = (it + 1) * 64;
      #pragma unroll
      for (int ch = 0; ch < 2; ch++) {
        #pragma unroll
        for (int i = 0; i < APW; i++)
          gld16(gA[i] + ko + ch * 32, As + ((p ^ 1) * 2 + ch) * TM * 32 + aoff[i]);
        #pragma unroll
        for (int i = 0; i < BPW; i++)
          gld16(gB[i] + ko + ch * 32, Bs + ((p ^ 1) * 2 + ch) * TN * 32 + boff[i]);
      }
    }
    #pragma unroll
    for (int ch = 0; ch < 2; ch++) {
      bf16x8 af[MT], bfr[NT];
      #pragma unroll
      for (int mt = 0; mt < MT; mt++)
        af[mt] = *(const bf16x8*)(As + (p * 2 + ch) * TM * 32 +
                                  (wm * (TM/2) + mt * 16 + ln) * 32 + g * 8);
      #pragma unroll
      for (int nt = 0; nt < NT; nt++)
        bfr[nt] = *(const bf16x8*)(Bs + (p * 2 + ch) * TN * 32 +
                                   (wn * (TN/2) + nt * 16 + ln) * 32 + g * 8);
      #pragma unroll
      for (int mt = 0; mt < MT; mt++)
        #pragma unroll
        for (int nt = 0; nt < NT; nt++)
          acc[mt][nt] = MFMA16(af[mt], bfr[nt], acc[mt][nt]);
    }
    p ^= 1;
  }

  CT* C = (CT*)D.C;
  #pragma unroll
  for (int mt = 0; mt < MT; mt++)
    #pragma unroll
    for (int r = 0; r < 4; r++) {
      int m = m0 + wm * (TM/2) + mt * 16 + g * 4 + r;
      #pragma unroll
      for (int nt = 0; nt < NT; nt++) {
        int n = n0 + wn * (TN/2) + nt * 16 + ln;
        if (n < D.Nvalid) C[(size_t)m * D.ldc + n] = (CT)acc[mt][nt][r];
      }
    }
}

// ---------------------------------------------------------------------------
// Fused prep: cast x -> bf16, build RoPE cos/sin table, transpose-cast all 8
// weights -- ONE launch (independent work; branch on blockIdx range).
// ---------------------------------------------------------------------------
struct TDescs {
  const float* src[8];
  __bf16* dst[8];
  int K[8];
  int N[8];
  int t0[9];
};

__global__ __launch_bounds__(256) void prep_all(
    const float* __restrict__ x, __bf16* __restrict__ xb,
    float2* __restrict__ rope, TDescs td) {
  __shared__ float t[32][33];
  const int nCast = (BT * DM) / 1024;   // 4096 blocks of cast work
  const int nTab  = (T_ * 16) / 256;    // 128 blocks of table work
  if ((int)blockIdx.x < nCast) {
    int i = (blockIdx.x * 256 + threadIdx.x) * 4;
    float4 v = *(const float4*)(x + i);
    bf16x4 o = { (__bf16)v.x, (__bf16)v.y, (__bf16)v.z, (__bf16)v.w };
    *(bf16x4*)(xb + i) = o;
    return;
  }
  if ((int)blockIdx.x < nCast + nTab) {
    int idx = (blockIdx.x - nCast) * 256 + threadIdx.x;  // 0..32767
    int tt = idx >> 4, jj = idx & 15;
    float invf = exp2f((float)jj * -0.8304820237f);      // 10000^(-jj/16)
    float ang = (float)tt * invf;
    float s, c;
    sincosf(ang, &s, &c);
    rope[idx] = make_float2(c, s);
    return;
  }
  int bx = blockIdx.x - nCast - nTab;
  int i = 7;
  while (bx < td.t0[i]) i--;
  int local = bx - td.t0[i];
  int ntn = td.N[i] >> 5;
  int kt = local / ntn;
  int nt = local - kt * ntn;
  const int ks = kt * 32, ns = nt * 32;
  const float* src = td.src[i];
  __bf16* dst = td.dst[i];
  const int N = td.N[i], K = td.K[i];
  const int tx = threadIdx.x & 31, ty = threadIdx.x >> 5;
  #pragma unroll
  for (int r = 0; r < 4; r++)
    t[ty + r * 8][tx] = src[(size_t)(ks + ty + r * 8) * N + ns + tx];
  __syncthreads();
  #pragma unroll
  for (int r = 0; r < 4; r++)
    dst[(size_t)(ns + ty + r * 8) * K + ks + tx] = (__bf16)t[tx][ty + r * 8];
}

// ---------------------------------------------------------------------------
// Assemble K only. RoPE angles from table (no per-lane trig).
// ---------------------------------------------------------------------------
__global__ __launch_bounds__(256) void assemble_k(
    const __bf16* __restrict__ kv,    // [BT][1024]: ks
    const __bf16* __restrict__ cqkr,  // [BT][672]: kr at cols 640..671
    const float2* __restrict__ rope,
    __bf16* __restrict__ kb) {
  int wid  = (blockIdx.x * blockDim.x + threadIdx.x) >> 6;
  int lane = threadIdx.x & 63;
  int h   = wid & (NH - 1);
  int row = wid >> 4;
  int b   = row >> 11;
  int t   = row & (T_ - 1);

  float v0k = (float)kv[(size_t)row * 1024 + h * DH + lane];
  float v1k = 0.f;
  if (lane < DR) {
    int jj = lane & 15;
    float2 cs = rope[t * 16 + jj];
    float kx1 = (float)cqkr[(size_t)row * 672 + 640 + jj];
    float kx2 = (float)cqkr[(size_t)row * 672 + 640 + 16 + jj];
    if (lane < 16) v1k = kx1 * cs.x - kx2 * cs.y;
    else           v1k = kx1 * cs.y + kx2 * cs.x;
  }
  float ssk = v0k * v0k + v1k * v1k;
  #pragma unroll
  for (int off = 32; off; off >>= 1)
    ssk += __shfl_xor(ssk, off);
  float sk = rsqrtf(ssk / 96.f + 1e-6f);
  size_t obase = ((size_t)(b * NH + h) * T_ + t) * DQK;
  kb[obase + lane] = (__bf16)(v0k * sk);
  if (lane < DR)
    kb[obase + DH + lane] = (__bf16)(v1k * sk);
}

// ---------------------------------------------------------------------------
// Fixed-max MFMA flash attention (causal), paired q-tiles, 8-wave blocks.
// r20 dbuf single-barrier + r19 swapped-QK reg-P + r23 k-permuted V + exp2
// + r24 in-kernel Q assembly + r25 rope table.
// r26: PROLOGUE LATENCY OVERLAP. r25 showed the Q-fusion cost is not VALU
//   (table removed trig, VALUBusy -4, duration flat) -- it's the serial
//   prologue chain (scattered Q loads -> rot -> shfl -> rsqrt) sitting
//   BEFORE the first staging issue. Reorder: issue tile-0 K/V global loads
//   first, then Q+table loads (stay in flight), then LDS writes + barrier
//   (Q loads complete underneath), then prologue math (VALU-only, ~200cy).
// ---------------------------------------------------------------------------
#define KS_STR 104   // K LDS row stride
#define VT_STR 72    // V LDS row stride (k-permuted layout, 64 used + 8 pad)
__global__ __launch_bounds__(512) void flash_mfma(
    const __bf16* __restrict__ qg,  // qsqr: [BT][1536] = qs | qr
    const __bf16* __restrict__ kg,
    const __bf16* __restrict__ vt,  // [b*1024 + h*64 + d][T_]  (V^T)
    const float2* __restrict__ rope,
    __bf16* __restrict__ ao) {
  __shared__ __align__(16) __bf16 Ksh[2][64 * KS_STR];   // 2 x 13312 B
  __shared__ __align__(16) __bf16 Vth[2][64 * VT_STR];   // 2 x  9216 B

  // load-balanced remap (r22, neutral but kept): halves complementary in ta
  const int lb   = blockIdx.y * 16 + blockIdx.x;
  const int half = lb >> 8;
  const int i    = lb & 255;
  const int tc   = i & 15;
  const int ta   = half ? (15 - tc) : tc;        // light tile 0..15
  const int hb   = (i >> 4) + half * 16;         // head-batch 0..31
  const int tb   = (T_ / 64 - 1) - ta;           // heavy tile 31..16

  const int bb = hb >> 4, h = hb & 15;
  const int w    = threadIdx.x >> 6;         // 0..7
  const int lane = threadIdx.x & 63;
  const int g    = lane >> 4;
  const int ln   = lane & 15;
  const int wi   = w & 3;
  const int tile = (w < 4) ? tb : ta;        // wave's tile
  const int qw   = tile * 64 + wi * 16;      // wave's 16 queries
  const size_t hbT = (size_t)hb * T_;
  const __bf16* vrow = vt + (size_t)(bb * 1024 + h * 64) * T_;

  const int ks0   = threadIdx.x;
  const int krow0 = ks0 / 12, kcol0 = ks0 % 12;
  const bool k1on = (threadIdx.x < 256);
  const int ks1   = 512 + threadIdx.x;
  const int krow1 = ks1 / 12, kcol1 = ks1 % 12;
  const int vr = threadIdx.x >> 3, vc = threadIdx.x & 7;
  const int vpA = ((vc >> 1) << 2) | ((vc & 1) << 5);   // k-permuted base

  // --- (1) issue tile-0 K/V global loads FIRST
  bf16x8 kreg0, kreg1, vreg;
  kreg0 = *(const bf16x8*)(kg + (hbT + krow0) * DQK + kcol0 * 8);
  if (k1on) kreg1 = *(const bf16x8*)(kg + (hbT + krow1) * DQK + kcol1 * 8);
  vreg = *(const bf16x8*)(vrow + (size_t)vr * T_ + vc * 8);

  // --- (2) issue Q + rope loads (independent; stay in flight under staging)
  const int tq = qw + ln;
  const size_t qrow = ((size_t)bb * T_ + tq) * 1536;
  bf16x8 qs0 = *(const bf16x8*)(qg + qrow + h * DH + g * 8);
  bf16x8 qs1 = *(const bf16x8*)(qg + qrow + h * DH + 32 + g * 8);
  bf16x8 qlo = *(const bf16x8*)(qg + qrow + 1024 + h * DR + (g & 1) * 8);
  bf16x8 qhi = *(const bf16x8*)(qg + qrow + 1024 + h * DR + 16 + (g & 1) * 8);
  const float2* trp = rope + tq * 16 + (g & 1) * 8;
  float2 csr[8];
  #pragma unroll
  for (int ii = 0; ii < 8; ii++) csr[ii] = trp[ii];

  // --- (3) LDS-write tile 0 (waits only the K/V loads) + barrier
  *(bf16x8*)(Ksh[0] + krow0 * KS_STR + kcol0 * 8) = kreg0;
  if (k1on) *(bf16x8*)(Ksh[0] + krow1 * KS_STR + kcol1 * 8) = kreg1;
  {
    __bf16* vd = Vth[0] + vr * VT_STR + vpA;
    *(bf16x4*)(vd)      = __builtin_shufflevector(vreg, vreg, 0, 1, 2, 3);
    *(bf16x4*)(vd + 16) = __builtin_shufflevector(vreg, vreg, 4, 5, 6, 7);
  }
  __syncthreads();

  // --- (4) prologue math (VALU-only): RoPE + RMS-norm + scale fold
  float rot[8];
  float ss = 0.f;
  #pragma unroll
  for (int ii = 0; ii < 8; ii++) {
    float lo = (float)qlo[ii], hi = (float)qhi[ii];
    rot[ii] = (g < 2) ? (lo * csr[ii].x - hi * csr[ii].y)
                      : (lo * csr[ii].y + hi * csr[ii].x);
    float a0 = (float)qs0[ii], a1 = (float)qs1[ii];
    ss += a0 * a0 + a1 * a1 + rot[ii] * rot[ii];
  }
  ss += __shfl_xor(ss, 16);
  ss += __shfl_xor(ss, 32);
  const float sq = rsqrtf(ss * (1.f / 96.f) + 1e-6f) * 0.14724431f;
  bf16x8 qf[3];
  #pragma unroll
  for (int ii = 0; ii < 8; ii++) {
    qf[0][ii] = (__bf16)((float)qs0[ii] * sq);
    qf[1][ii] = (__bf16)((float)qs1[ii] * sq);
    qf[2][ii] = (__bf16)(rot[ii] * sq);
  }

  f32x4 o[4];
  #pragma unroll
  for (int nt = 0; nt < 4; nt++) o[nt] = (f32x4){0.f, 0.f, 0.f, 0.f};
  float lsum0 = 0.f, lsum1 = 0.f;

  const int kmax = (tb + 1) * 64;

  int p = 0;
  for (int k0 = 0; k0 < kmax; k0 += 64) {
    const bool havenext = (k0 + 64 < kmax);
    if (havenext) {   // prefetch next tile into regs (hidden by compute)
      kreg0 = *(const bf16x8*)(kg + (hbT + k0 + 64 + krow0) * DQK + kcol0 * 8);
      if (k1on)
        kreg1 = *(const bf16x8*)(kg + (hbT + k0 + 64 + krow1) * DQK + kcol1 * 8);
      vreg = *(const bf16x8*)(vrow + (size_t)vr * T_ + k0 + 64 + vc * 8);
    }

    if (k0 <= qw + 15) {   // wave-uniform causal skip
      const __bf16* Kp = Ksh[p];
      const __bf16* Vp = Vth[p];
      // QK^T swapped: sa[ks] = S^T tile, row=key k0+ks*16+g*4+r, col=q=qw+ln
      f32x4 sa[4];
      #pragma unroll
      for (int ks = 0; ks < 4; ks++) sa[ks] = (f32x4){0.f, 0.f, 0.f, 0.f};
      #pragma unroll
      for (int s = 0; s < 3; s++)
        #pragma unroll
        for (int ks = 0; ks < 4; ks++) {
          bf16x8 kf = *(const bf16x8*)(Kp + (ks * 16 + ln) * KS_STR + s * 32 + g * 8);
          sa[ks] = MFMA16(kf, qf[s], sa[ks]);
        }
      const bool diag = (k0 + 63 > qw);
      bf16x4 bq[4];
      #pragma unroll
      for (int ks = 0; ks < 4; ks++)
        #pragma unroll
        for (int r = 0; r < 4; r++) {
          float pe = exp2_fast(sa[ks][r]);
          if (diag) {
            int key = k0 + ks * 16 + g * 4 + r;
            if (key > qw + ln) pe = 0.f;
          }
          if (ks & 2) lsum1 += pe; else lsum0 += pe;
          bq[ks][r] = (__bf16)pe;
        }
      // PV: O^T = V^T . P^T; V fragments for all 4 ks come from 2 b128 reads
      #pragma unroll
      for (int nt = 0; nt < 4; nt++) {
        const __bf16* vb = Vp + (nt * 16 + ln) * VT_STR + g * 16;
        bf16x8 vA = *(const bf16x8*)(vb);       // ks0 | ks1
        bf16x8 vB = *(const bf16x8*)(vb + 8);   // ks2 | ks3
        o[nt] = mfma_pv(__builtin_shufflevector(vA, vA, 0, 1, 2, 3), bq[0], o[nt]);
        o[nt] = mfma_pv(__builtin_shufflevector(vA, vA, 4, 5, 6, 7), bq[1], o[nt]);
        o[nt] = mfma_pv(__builtin_shufflevector(vB, vB, 0, 1, 2, 3), bq[2], o[nt]);
        o[nt] = mfma_pv(__builtin_shufflevector(vB, vB, 4, 5, 6, 7), bq[3], o[nt]);
      }
    }

    if (havenext) {   // write next tile into the other buffer
      *(bf16x8*)(Ksh[p ^ 1] + krow0 * KS_STR + kcol0 * 8) = kreg0;
      if (k1on) *(bf16x8*)(Ksh[p ^ 1] + krow1 * KS_STR + kcol1 * 8) = kreg1;
      __bf16* vd = Vth[p ^ 1] + vr * VT_STR + vpA;
      *(bf16x4*)(vd)      = __builtin_shufflevector(vreg, vreg, 0, 1, 2, 3);
      *(bf16x4*)(vd + 16) = __builtin_shufflevector(vreg, vreg, 4, 5, 6, 7);
    }
    __syncthreads();
    p ^= 1;
  }

  float s = lsum0 + lsum1;
  s += __shfl_xor(s, 16);
  s += __shfl_xor(s, 32);
  const float linv = 1.0f / s;

  const size_t obase = (size_t)(bb * T_ + qw + ln) * DM + h * DH;
  #pragma unroll
  for (int nt = 0; nt < 4; nt++) {
    bf16x4 ov = { (__bf16)(o[nt][0] * linv), (__bf16)(o[nt][1] * linv),
                  (__bf16)(o[nt][2] * linv), (__bf16)(o[nt][3] * linv) };
    *(bf16x4*)(ao + obase + nt * 16 + g * 4) = ov;
  }
}

// ---------------------------------------------------------------------------
extern "C" void kernel_launch(void* const* d_in, const int* in_sizes, int n_in,
                              void* d_out, int out_size, void* d_ws, size_t ws_size,
                              hipStream_t stream) {
  const float* x     = (const float*)d_in[0];
  const float* w_dq  = (const float*)d_in[1];
  const float* w_uq  = (const float*)d_in[2];
  const float* w_rq  = (const float*)d_in[3];
  const float* w_dkv = (const float*)d_in[4];
  const float* w_rk  = (const float*)d_in[5];
  const float* w_uk  = (const float*)d_in[6];
  const float* w_uv  = (const float*)d_in[7];
  const float* w_o   = (const float*)d_in[8];
  float* out = (float*)d_out;

  __bf16* p = (__bf16*)d_ws;
  __bf16* xb   = p;  p += (size_t)BT * DM;
  __bf16* B1t  = p;  p += (size_t)672 * 1024;
  __bf16* B2t  = p;  p += (size_t)1536 * 384;
  __bf16* B3t  = p;  p += (size_t)2048 * 256;   // w_uk^T | w_uv^T
  __bf16* B4t  = p;  p += (size_t)1024 * 1024;
  __bf16* cqkr = p;  p += (size_t)BT * 672;     // c_q | c_kv | kr
  __bf16* qsqr = p;  p += (size_t)BT * 1536;    // qs | qr (read by flash)
  __bf16* kv   = p;  p += (size_t)BT * 1024;    // ks
  __bf16* vt   = p;  p += (size_t)BT * 1024;    // V^T [b*1024+h*64+d][T]
  __bf16* kb   = p;  p += (size_t)B_ * NH * T_ * DQK;
  float2* rope = (float2*)p;  p += (size_t)T_ * 16 * 4;  // 256 KB table
  __bf16* aob  = xb;   // xb dead after G1

  // Fused prep: cast x + RoPE table + transpose-cast all 8 weights
  {
    TDescs td;
    const float* srcs[8] = {w_dq, w_dkv, w_rk, w_uq, w_rq, w_uk, w_uv, w_o};
    __bf16* dsts[8] = {B1t, B1t + (size_t)384 * 1024, B1t + (size_t)640 * 1024,
                       B2t, B2t + (size_t)1024 * 384,
                       B3t, B3t + (size_t)1024 * 256, B4t};
    int Ks[8] = {1024, 1024, 1024, 384, 384, 256, 256, 1024};
    int Ns[8] = {384, 256, 32, 1024, 512, 1024, 1024, 1024};
    int acc = 0;
    for (int i = 0; i < 8; i++) {
      td.src[i] = srcs[i]; td.dst[i] = dsts[i];
      td.K[i] = Ks[i]; td.N[i] = Ns[i];
      td.t0[i] = acc;
      acc += (Ks[i] / 32) * (Ns[i] / 32);
    }
    td.t0[8] = acc;
    prep_all<<<(BT * DM) / 1024 + (T_ * 16) / 256 + acc, 256, 0, stream>>>(
        x, xb, rope, td);
  }

  // G1: cqkr = xb @ B1t^T   (64x64, BK=64, 4-wave: 704 blocks)  [r14 proven]
  {
    GemmBatch g; g.nd = 1;
    g.d[0] = GemmDesc{xb, B1t, (void*)cqkr, DM, 1024, 672, 1024, 672, 11, 0};
    gemm_multi<__bf16, 64, 64><<<704, 256, 0, stream>>>(g);
  }
  // Fused: G2, G3, VT b0/b1 -> 128x128 tiles (m97 density): 896 blocks
  {
    GemmBatch g; g.nd = 4;
    g.d[0] = GemmDesc{cqkr, B2t, (void*)qsqr, 672, 384, 1536, 384, 1536, 12, 0};
    g.d[1] = GemmDesc{cqkr + 384, B3t, (void*)kv, 672, 256, 1024, 256, 1024, 8, 384};
    g.d[2] = GemmDesc{B3t + (size_t)1024 * 256, cqkr + 384, (void*)vt,
                      256, 672, T_, 256, T_, 16, 640};
    g.d[3] = GemmDesc{B3t + (size_t)1024 * 256, cqkr + (size_t)T_ * 672 + 384,
                      (void*)(vt + (size_t)1024 * T_), 256, 672, T_, 256, T_, 16, 768};
    gemm_multi<__bf16, 128, 128><<<896, 256, 0, stream>>>(g);
  }

  // RoPE + concat + RMS-norm for K only (Q fused into flash; table-driven)
  assemble_k<<<(BT * NH) / 4, 256, 0, stream>>>(kv, cqkr, rope, kb);

  // Paired-tile fixed-max causal MFMA flash attention (8-wave, overlapped Q)
  flash_mfma<<<dim3(T_ / 128, B_ * NH), 512, 0, stream>>>(qsqr, kb, vt, rope, aob);

  // G4: out = aob @ B4t^T  (fp32 out, 64x64, BK=64, 4-wave: 1024 blocks) [r14]
  {
    GemmBatch g; g.nd = 1;
    g.d[0] = GemmDesc{aob, B4t, (void*)out, DM, 1024, DM, 1024, 1024, 16, 0};
    gemm_multi<float, 64, 64><<<1024, 256, 0, stream>>>(g);
  }
}